// Round 15
// baseline (178.031 us; speedup 1.0000x reference)
//
#include <hip/hip_runtime.h>
#include <stdint.h>
#include <math.h>

// Problem constants
#define NPTS 32768
#define PP   5
#define MM   1024
#define JJ   24
#define HH   256

// out (f32 element offsets), total 2,293,760 floats
#define O0 0                // tpose        [1,N,P,3]
#define O1 491520           // tpose_dirs   [1,N,P,3]
#define O2 983040           // resd         [1,N,P,3]
#define O3 1474560          // pflag        [1,N,P]
#define O4 1638400          // init_bigpose [1,N*P,3]
#define O5 2129920          // pnorm        [1,N*P]

typedef unsigned short ushort_t;
typedef unsigned int   uint_t;
typedef unsigned long long u64_t;
typedef __attribute__((ext_vector_type(8))) short bf16x8;
typedef __attribute__((ext_vector_type(4))) float f32x4;

__device__ __forceinline__ ushort_t f2bf(float f) {
  union { uint_t i; float f; } v; v.f = f;
  uint_t i = v.i;
  return (ushort_t)((i + 0x7FFFu + ((i >> 16) & 1u)) >> 16);  // RNE
}
// hardware packed f32->bf16 (RNE, bit-identical to f2bf for finite values)
__device__ __forceinline__ uint_t cvt_pk_bf16(float lo, float hi) {
  uint_t r;
  asm("v_cvt_pk_bf16_f32 %0, %1, %2" : "=v"(r) : "v"(lo), "v"(hi));
  return r;
}
__device__ __forceinline__ float tanh_fast(float v) {
  v = fminf(fmaxf(v, -15.f), 15.f);
  float e = __expf(2.f*v);               // v_exp_f32 path
  return __fdividef(e - 1.f, e + 1.f);   // abs err < 1e-6, plenty for tolerance
}
// 16-lane sum via DPP row_shl tree (VALU pipe). Result in lane m16==0.
__device__ __forceinline__ float dpp_sum16(float x) {
  x += __int_as_float(__builtin_amdgcn_update_dpp(0, __float_as_int(x), 0x108, 0xF, 0xF, true)); // row_shl:8
  x += __int_as_float(__builtin_amdgcn_update_dpp(0, __float_as_int(x), 0x104, 0xF, 0xF, true)); // row_shl:4
  x += __int_as_float(__builtin_amdgcn_update_dpp(0, __float_as_int(x), 0x102, 0xF, 0xF, true)); // row_shl:2
  x += __int_as_float(__builtin_amdgcn_update_dpp(0, __float_as_int(x), 0x101, 0xF, 0xF, true)); // row_shl:1
  return x;
}
__device__ __forceinline__ float sel8f(const float* a, int s) {
  float v = a[0];
  v = (s==1)?a[1]:v; v = (s==2)?a[2]:v; v = (s==3)?a[3]:v;
  v = (s==4)?a[4]:v; v = (s==5)?a[5]:v; v = (s==6)?a[6]:v; v = (s==7)?a[7]:v;
  return v;
}
__device__ __forceinline__ u64_t sel8u(const u64_t* a, int s) {
  u64_t v = a[0];
  v = (s==1)?a[1]:v; v = (s==2)?a[2]:v; v = (s==3)?a[3]:v;
  v = (s==4)?a[4]:v; v = (s==5)?a[5]:v; v = (s==6)?a[6]:v; v = (s==7)?a[7]:v;
  return v;
}

// ---------------- LBS transform for one (n,p) row ----------------
__device__ __forceinline__ void transform_one(
    int n, int p, int nn, float pn, float fl,
    float px, float py, float pz, float dx, float dy, float dz,
    const float* __restrict__ pbw,
    const float4* __restrict__ sA4, const float4* __restrict__ sB4,
    float* __restrict__ out)
{
  const float4* bwr = (const float4*)(pbw + ((size_t)p * MM + nn) * JJ);
  float bw[24];
  #pragma unroll
  for (int q = 0; q < 6; ++q) {
    float4 u = bwr[q];
    bw[q*4+0] = u.x; bw[q*4+1] = u.y; bw[q*4+2] = u.z; bw[q*4+3] = u.w;
  }

  float M1[12], M2[12];
  #pragma unroll
  for (int q = 0; q < 12; ++q) { M1[q] = 0.f; M2[q] = 0.f; }
  #pragma unroll
  for (int j = 0; j < 24; ++j) {
    float w = bw[j];
    float4 a0 = sA4[j*3+0], a1 = sA4[j*3+1], a2 = sA4[j*3+2];
    M1[0]=fmaf(w,a0.x,M1[0]); M1[1]=fmaf(w,a0.y,M1[1]); M1[2]=fmaf(w,a0.z,M1[2]); M1[3]=fmaf(w,a0.w,M1[3]);
    M1[4]=fmaf(w,a1.x,M1[4]); M1[5]=fmaf(w,a1.y,M1[5]); M1[6]=fmaf(w,a1.z,M1[6]); M1[7]=fmaf(w,a1.w,M1[7]);
    M1[8]=fmaf(w,a2.x,M1[8]); M1[9]=fmaf(w,a2.y,M1[9]); M1[10]=fmaf(w,a2.z,M1[10]); M1[11]=fmaf(w,a2.w,M1[11]);
    float4 c0 = sB4[j*3+0], c1 = sB4[j*3+1], c2 = sB4[j*3+2];
    M2[0]=fmaf(w,c0.x,M2[0]); M2[1]=fmaf(w,c0.y,M2[1]); M2[2]=fmaf(w,c0.z,M2[2]); M2[3]=fmaf(w,c0.w,M2[3]);
    M2[4]=fmaf(w,c1.x,M2[4]); M2[5]=fmaf(w,c1.y,M2[5]); M2[6]=fmaf(w,c1.z,M2[6]); M2[7]=fmaf(w,c1.w,M2[7]);
    M2[8]=fmaf(w,c2.x,M2[8]); M2[9]=fmaf(w,c2.y,M2[9]); M2[10]=fmaf(w,c2.z,M2[10]); M2[11]=fmaf(w,c2.w,M2[11]);
  }
  float a=M1[0], b=M1[1], c=M1[2];
  float d=M1[4], e=M1[5], f=M1[6];
  float g=M1[8], h=M1[9], i=M1[10];
  float C00 = e*i - f*h, C01 = c*h - b*i, C02 = b*f - c*e;
  float C10 = f*g - d*i, C11 = a*i - c*g, C12 = c*d - a*f;
  float C20 = d*h - e*g, C21 = b*g - a*h, C22 = a*e - b*d;
  float det = a*C00 + b*C10 + c*C20;
  float rd = 1.0f / det;
  float tx = px - M1[3], ty = py - M1[7], tz = pz - M1[11];
  float t0 = rd * (C00*tx + C01*ty + C02*tz);
  float t1 = rd * (C10*tx + C11*ty + C12*tz);
  float t2 = rd * (C20*tx + C21*ty + C22*tz);
  float i0 = M2[0]*t0 + M2[1]*t1 + M2[2]*t2  + M2[3];
  float i1 = M2[4]*t0 + M2[5]*t1 + M2[6]*t2  + M2[7];
  float i2 = M2[8]*t0 + M2[9]*t1 + M2[10]*t2 + M2[11];
  float d0 = rd * (C00*dx + C01*dy + C02*dz);
  float d1 = rd * (C10*dx + C11*dy + C12*dz);
  float d2 = rd * (C20*dx + C21*dy + C22*dz);
  float e0 = M2[0]*d0 + M2[1]*d1 + M2[2]*d2;
  float e1 = M2[4]*d0 + M2[5]*d1 + M2[6]*d2;
  float e2 = M2[8]*d0 + M2[9]*d1 + M2[10]*d2;

  size_t k = (size_t)n * PP + p;   // n-major
  out[O1 + k*3+0] = e0; out[O1 + k*3+1] = e1; out[O1 + k*3+2] = e2;
  out[O3 + k] = fl;
  out[O4 + k*3+0] = i0; out[O4 + k*3+1] = i1; out[O4 + k*3+2] = i2;
  out[O5 + k] = pn;
}

// grid: 1536 blocks x 128 threads. Blocks >=1280 do the W2->bf16 prep (2 n's
// per thread). Blocks <1280: p = b>>8, 128 n's; 16 groups x 8 m-slices x
// EIGHT points per lane: each 4x ds_read_b128 per 32-block now feeds 32
// distances (2x the r14 reuse) -> LDS-pipe load halves relative to VALU
// (r14 counters: VALUBusy 68%, ~30% idle on lgkm queueing at ~80% LDS-pipe
// utilization). Distance expr = component-wise expansion of the verified r6
// f32x2 form (same association, pre-doubled coords) -> bit-identical. Raw
// coords for the transform recovered exactly as 0.5f*(2x). Block-min +
// deterministic-replay argmin as in r13/r14. All 8 lanes of a group now
// transform one point each (100% lane efficiency).
__global__ __launch_bounds__(128) void nn_kernel(
    const float* __restrict__ pp0, const float* __restrict__ pp1,
    const float* __restrict__ part_pts, const float* __restrict__ pbw,
    const float* __restrict__ Ag, const float* __restrict__ Bg,
    const int* __restrict__ lengths2,
    const float* __restrict__ W2g, ushort_t* __restrict__ W2bf,
    float* __restrict__ out)
{
  // folded W2 prep: blocks 1280..1535, k = bid-1280, 2 n's per thread
  if (blockIdx.x >= 1280) {
    int k = blockIdx.x - 1280;
    int kc = k >> 5, quad = (k & 31) >> 3, j = k & 7;
    #pragma unroll
    for (int h = 0; h < 2; ++h) {
      int n = threadIdx.x + h*128;
      float v = W2g[k*256 + n];
      int tile = n >> 4, lane = quad*16 + (n & 15);
      W2bf[kc*8192 + tile*512 + lane*8 + j] = f2bf(v);
    }
    return;
  }

  __shared__ float4 sXq[256], sYq[256], sZq[256], sWq[256];  // SoA quads
  __shared__ float4 sA4[72];
  __shared__ float4 sB4[72];
  int t = threadIdx.x;             // 0..127 (2 waves)
  int p  = blockIdx.x >> 8;        // 256 blocks per part
  int nb = blockIdx.x & 255;
  int g  = t >> 3;                 // n-group 0..15
  int s  = t & 7;                  // m-slice 0..7
  int n0 = nb*128 + g*8;           // this lane's 8 points: n0..n0+7

  // pose-pair disambiguation (wave-uniform); pose_dirs rows unit-norm
  float s0r0 = pp0[0], s0r1 = pp0[1], s0r2 = pp0[2];
  float nrm = s0r0*s0r0 + s0r1*s0r1 + s0r2*s0r2;
  bool c0_is_dirs = fabsf(nrm - 1.0f) < 1e-4f;
  const float* pose_pts  = c0_is_dirs ? pp1 : pp0;
  const float* pose_dirs = c0_is_dirs ? pp0 : pp1;

  {
    #pragma clang fp contract(off)
    float* fX = (float*)sXq; float* fY = (float*)sYq;
    float* fZ = (float*)sZq; float* fW = (float*)sWq;
    for (int i = t; i < MM; i += 128) {
      float x = part_pts[((size_t)p*MM+i)*3+0];
      float y = part_pts[((size_t)p*MM+i)*3+1];
      float z = part_pts[((size_t)p*MM+i)*3+2];
      float yy = ((x*x) + (y*y)) + (z*z);
      fX[i] = x; fY[i] = y; fZ[i] = z; fW[i] = yy;
    }
  }
  for (int i = t; i < 72; i += 128) {
    int l = i*4;
    int j = l / 12, rc = l % 12;
    float4 qa, qb;
    qa.x = Ag[j*16+rc+0]; qa.y = Ag[j*16+rc+1]; qa.z = Ag[j*16+rc+2]; qa.w = Ag[j*16+rc+3];
    qb.x = Bg[j*16+rc+0]; qb.y = Bg[j*16+rc+1]; qb.z = Bg[j*16+rc+2]; qb.w = Bg[j*16+rc+3];
    sA4[i] = qa; sB4[i] = qb;
  }
  int mlen = lengths2[p]; if (mlen > MM) mlen = MM;
  __syncthreads();

  // 8 points' coords (n0 % 8 == 0 -> aligned float4 span of 6); doubled + |x|^2
  float Xd[8], Yd[8], Zd[8], C2[8];
  {
    #pragma clang fp contract(off)
    const float4* pr = (const float4*)(pose_pts + (size_t)n0*3);
    float4 f0 = pr[0], f1 = pr[1], f2 = pr[2], f3 = pr[3], f4 = pr[4], f5 = pr[5];
    float X[8], Y[8], Z[8];
    X[0]=f0.x; Y[0]=f0.y; Z[0]=f0.z;
    X[1]=f0.w; Y[1]=f1.x; Z[1]=f1.y;
    X[2]=f1.z; Y[2]=f1.w; Z[2]=f2.x;
    X[3]=f2.y; Y[3]=f2.z; Z[3]=f2.w;
    X[4]=f3.x; Y[4]=f3.y; Z[4]=f3.z;
    X[5]=f3.w; Y[5]=f4.x; Z[5]=f4.y;
    X[6]=f4.z; Y[6]=f4.w; Z[6]=f5.x;
    X[7]=f5.y; Y[7]=f5.z; Z[7]=f5.w;
    #pragma unroll
    for (int j = 0; j < 8; ++j) {
      C2[j] = ((X[j]*X[j]) + (Y[j]*Y[j])) + (Z[j]*Z[j]);
      Xd[j] = 2.0f*X[j]; Yd[j] = 2.0f*Y[j]; Zd[j] = 2.0f*Z[j];
    }
  }

  float best[8];
  int   kb[8], mbest[8];
  #pragma unroll
  for (int j = 0; j < 8; ++j) { best[j] = INFINITY; kb[j] = 0; mbest[j] = 0; }
  int nq = mlen >> 5;              // full 32-blocks
  {
    #pragma clang fp contract(off)
    for (int k = 0; k < nq; ++k) {
      int qi = k*8 + s;            // quad index (8-way same-addr broadcast)
      float4 QX = sXq[qi], QY = sYq[qi], QZ = sZq[qi], QW = sWq[qi];
      #pragma unroll
      for (int j = 0; j < 8; ++j) {
        float dA = ((Xd[j]*QX.x) + (Yd[j]*QY.x)) + (Zd[j]*QZ.x);
        float eA = fmaxf((C2[j] - dA) + QW.x, 0.f);
        float dB = ((Xd[j]*QX.y) + (Yd[j]*QY.y)) + (Zd[j]*QZ.y);
        float eB = fmaxf((C2[j] - dB) + QW.y, 0.f);
        float dC = ((Xd[j]*QX.z) + (Yd[j]*QY.z)) + (Zd[j]*QZ.z);
        float eC = fmaxf((C2[j] - dC) + QW.z, 0.f);
        float dD = ((Xd[j]*QX.w) + (Yd[j]*QY.w)) + (Zd[j]*QZ.w);
        float eD = fmaxf((C2[j] - dD) + QW.w, 0.f);
        float m01 = fminf(eA, eB);
        float m23 = fminf(eC, eD);
        float lmin = fminf(m01, m23);
        bool lt = lmin < best[j];          // strict: first block keeps win
        best[j] = fminf(best[j], lmin);
        kb[j] = lt ? k : kb[j];
      }
    }
    // deterministic replay of the winning block -> exact first-min index
    if (nq > 0) {
      #pragma unroll
      for (int j = 0; j < 8; ++j) {
        int qi = kb[j]*8 + s;
        float4 QX = sXq[qi], QY = sYq[qi], QZ = sZq[qi], QW = sWq[qi];
        float dA = ((Xd[j]*QX.x) + (Yd[j]*QY.x)) + (Zd[j]*QZ.x);
        float eA = fmaxf((C2[j] - dA) + QW.x, 0.f);
        float dB = ((Xd[j]*QX.y) + (Yd[j]*QY.y)) + (Zd[j]*QZ.y);
        float eB = fmaxf((C2[j] - dB) + QW.y, 0.f);
        float dC = ((Xd[j]*QX.z) + (Yd[j]*QY.z)) + (Zd[j]*QZ.z);
        float eC = fmaxf((C2[j] - dC) + QW.z, 0.f);
        // first element equal to best (element 3 implied if others miss)
        int e = (eA == best[j]) ? 0 : (eB == best[j]) ? 1 : (eC == best[j]) ? 2 : 3;
        mbest[j] = (kb[j] << 5) + 4*s + e;
      }
    } else {
      #pragma unroll
      for (int j = 0; j < 8; ++j) mbest[j] = 4*s;
    }
    // tail: partial 32-block (not taken when mlen % 32 == 0)
    int mb0 = nq << 5;
    if (mb0 < mlen) {
      const float* fX = (const float*)sXq; const float* fY = (const float*)sYq;
      const float* fZ = (const float*)sZq; const float* fW = (const float*)sWq;
      #pragma unroll
      for (int e = 0; e < 4; ++e) {
        int m = mb0 + 4*s + e;
        if (m < mlen) {
          float qx = fX[m], qy = fY[m], qz = fZ[m], qw = fW[m];
          #pragma unroll
          for (int j = 0; j < 8; ++j) {
            float dt2 = ((Xd[j]*qx) + (Yd[j]*qy)) + (Zd[j]*qz);
            float dd = fmaxf((C2[j] - dt2) + qw, 0.0f);
            bool lt = dd < best[j];        // strict: earlier m wins ties
            best[j] = fminf(best[j], dd);
            mbest[j] = lt ? m : mbest[j];
          }
        }
      }
    }
  }

  // merge the 8 slices (butterfly within each 8-lane group), lexicographic
  u64_t pk[8];
  #pragma unroll
  for (int j = 0; j < 8; ++j) {
    pk[j] = ((u64_t)__float_as_uint(best[j]) << 32) | (uint_t)mbest[j];
    u64_t o;
    o = __shfl_xor(pk[j], 1); if (o < pk[j]) pk[j] = o;
    o = __shfl_xor(pk[j], 2); if (o < pk[j]) pk[j] = o;
    o = __shfl_xor(pk[j], 4); if (o < pk[j]) pk[j] = o;
  }

  // every lane transforms one point: lane s -> point j = s (static selects)
  {
    u64_t mypk = sel8u(pk, s);
    float xa = 0.5f * sel8f(Xd, s);   // exact: 0.5*(2x) == x
    float ya = 0.5f * sel8f(Yd, s);
    float za = 0.5f * sel8f(Zd, s);
    int n = n0 + s;
    int bm = (int)(mypk & 0xFFFFFFFFull);
    float bd = __uint_as_float((uint_t)(mypk >> 32));
    float pn = sqrtf(bd);
    float fl = ((double)pn < 0.08) ? 1.0f : 0.0f;
    float dxa = pose_dirs[n*3+0], dya = pose_dirs[n*3+1], dza = pose_dirs[n*3+2];
    transform_one(n, p, bm, pn, fl, xa, ya, za, dxa, dya, dza, pbw, sA4, sB4, out);
  }
}

// ---------------- MLP: r14-verified (conflict-free build) ----------------
__global__ __launch_bounds__(256) void mlp_kernel(
    const float* __restrict__ W1g, const float* __restrict__ b1g,
    const float* __restrict__ b2g, const float* __restrict__ W3g,
    const float* __restrict__ b3g, const ushort_t* __restrict__ W2bf,
    float* __restrict__ out)
{
  __shared__ ushort_t sH[4*8*512];   // 32KB: h1 A-frags [mt][kc][qd*16+r15][8]
  __shared__ float4 w1c[256];        // {W1[0][c], W1[1][c], W1[2][c], b1[c]}
  __shared__ float4 w3b2[256];       // {W3[c][0], W3[c][1], W3[c][2], b2[c]}
  __shared__ float4 sRow[64];        // {x, y, z, pflag} per row
  __shared__ float  prt[64][4][3];   // per-row layer-3 partials per wave

  int t = threadIdx.x;
  int wave = t >> 6, lane = t & 63, quad = lane >> 4, m16 = lane & 15;
  size_t row0 = (size_t)blockIdx.x * 64;

  {
    int c = t;   // 256 threads exactly
    w1c[c]  = make_float4(W1g[c], W1g[256+c], W1g[512+c], b1g[c]);
    w3b2[c] = make_float4(W3g[c*3+0], W3g[c*3+1], W3g[c*3+2], b2g[c]);
    if (t < 64) {
      size_t r = row0 + t;
      sRow[t] = make_float4(out[O4 + r*3+0], out[O4 + r*3+1], out[O4 + r*3+2],
                            out[O3 + r]);
    }
  }
  __syncthreads();

  // build sH: thread t -> row r = t&63; octets o = (t>>6)*8 + j (j=0..7).
  // Store lanes vary r15 -> bank-spread writes; w1c reads wave-uniform.
  {
    int r = t & 63;
    float4 xyz = sRow[r];
    int mt = r >> 4, r15 = r & 15;
    #pragma unroll
    for (int j = 0; j < 8; ++j) {
      int o = wave*8 + j;
      int kcw = o >> 2, qd = o & 3;
      int c0 = kcw*32 + qd*8;
      uint_t u0, u1, u2, u3;
      {
        float4 wA = w1c[c0 + 0], wB = w1c[c0 + 1];
        float hA = fmaxf(fmaf(xyz.z, wA.z, fmaf(xyz.y, wA.y, fmaf(xyz.x, wA.x, wA.w))), 0.f);
        float hB = fmaxf(fmaf(xyz.z, wB.z, fmaf(xyz.y, wB.y, fmaf(xyz.x, wB.x, wB.w))), 0.f);
        u0 = cvt_pk_bf16(hA, hB);
      }
      {
        float4 wA = w1c[c0 + 2], wB = w1c[c0 + 3];
        float hA = fmaxf(fmaf(xyz.z, wA.z, fmaf(xyz.y, wA.y, fmaf(xyz.x, wA.x, wA.w))), 0.f);
        float hB = fmaxf(fmaf(xyz.z, wB.z, fmaf(xyz.y, wB.y, fmaf(xyz.x, wB.x, wB.w))), 0.f);
        u1 = cvt_pk_bf16(hA, hB);
      }
      {
        float4 wA = w1c[c0 + 4], wB = w1c[c0 + 5];
        float hA = fmaxf(fmaf(xyz.z, wA.z, fmaf(xyz.y, wA.y, fmaf(xyz.x, wA.x, wA.w))), 0.f);
        float hB = fmaxf(fmaf(xyz.z, wB.z, fmaf(xyz.y, wB.y, fmaf(xyz.x, wB.x, wB.w))), 0.f);
        u2 = cvt_pk_bf16(hA, hB);
      }
      {
        float4 wA = w1c[c0 + 6], wB = w1c[c0 + 7];
        float hA = fmaxf(fmaf(xyz.z, wA.z, fmaf(xyz.y, wA.y, fmaf(xyz.x, wA.x, wA.w))), 0.f);
        float hB = fmaxf(fmaf(xyz.z, wB.z, fmaf(xyz.y, wB.y, fmaf(xyz.x, wB.x, wB.w))), 0.f);
        u3 = cvt_pk_bf16(hA, hB);
      }
      *(uint4*)(&sH[((mt*8 + kcw)*64 + qd*16 + r15)*8]) = make_uint4(u0, u1, u2, u3);
    }
  }
  __syncthreads();

  // K-loop: wave owns cols nt in [wave*4, wave*4+4)
  const ushort_t* Wlane = W2bf + (size_t)wave*2048 + lane*8;
  bf16x8 Bcur[4], Bnxt[4];
  #pragma unroll
  for (int q = 0; q < 4; ++q) Bcur[q] = *(const bf16x8*)(Wlane + q*512);  // kc=0

  f32x4 acc[16];                   // acc[mt*4+q]
  #pragma unroll
  for (int i = 0; i < 16; ++i) acc[i] = (f32x4){0.f,0.f,0.f,0.f};

  #pragma unroll 1
  for (int kc = 0; kc < 8; ++kc) {
    bf16x8 Af[4];
    #pragma unroll
    for (int mt = 0; mt < 4; ++mt)
      Af[mt] = *(const bf16x8*)(&sH[((mt*8 + kc)*64 + lane)*8]);
    if (kc < 7) {                  // prefetch next kc's B under this kc's MFMAs
      #pragma unroll
      for (int q = 0; q < 4; ++q)
        Bnxt[q] = *(const bf16x8*)(Wlane + (kc+1)*8192 + q*512);
    }
    #pragma unroll
    for (int mt = 0; mt < 4; ++mt)
      #pragma unroll
      for (int q = 0; q < 4; ++q)
        acc[mt*4+q] = __builtin_amdgcn_mfma_f32_16x16x32_bf16(Af[mt], Bcur[q], acc[mt*4+q], 0, 0, 0);
    if (kc < 7) {
      #pragma unroll
      for (int q = 0; q < 4; ++q) Bcur[q] = Bnxt[q];
    }
  }

  // epilogue: h2[row=mt*16+quad*4+reg][col=(wave*4+q)*16+m16] = acc[mt*4+q][reg]
  float4 cvq[4];
  #pragma unroll
  for (int q = 0; q < 4; ++q) cvq[q] = w3b2[(wave*4+q)*16 + m16];

  #pragma unroll
  for (int mt = 0; mt < 4; ++mt) {
    #pragma unroll
    for (int reg = 0; reg < 4; ++reg) {
      float q0 = 0.f, q1 = 0.f, q2 = 0.f;
      #pragma unroll
      for (int q = 0; q < 4; ++q) {
        float h2 = fmaxf(acc[mt*4+q][reg] + cvq[q].w, 0.f);
        q0 = fmaf(h2, cvq[q].x, q0);
        q1 = fmaf(h2, cvq[q].y, q1);
        q2 = fmaf(h2, cvq[q].z, q2);
      }
      q0 = dpp_sum16(q0);
      q1 = dpp_sum16(q1);
      q2 = dpp_sum16(q2);
      if (m16 == 0) {
        int lr = mt*16 + quad*4 + reg;           // local row 0..63
        prt[lr][wave][0] = q0;
        prt[lr][wave][1] = q1;
        prt[lr][wave][2] = q2;
      }
    }
  }
  __syncthreads();

  // combine: thread t -> (row = t>>2, comp = t&3), comp<3 active
  {
    int lr = t >> 2, c = t & 3;
    if (c < 3) {
      float v = ((prt[lr][0][c] + prt[lr][1][c]) + prt[lr][2][c]) + prt[lr][3][c];
      size_t r = row0 + lr;
      float4 ib = sRow[lr];
      float iv = (c == 0) ? ib.x : (c == 1) ? ib.y : ib.z;
      float rr = 0.05f * tanh_fast(v + b3g[c]) * ib.w;
      out[O0 + r*3 + c] = iv + rr;
      out[O2 + r*3 + c] = rr;
    }
  }
}

extern "C" void kernel_launch(void* const* d_in, const int* in_sizes, int n_in,
                              void* d_out, int out_size, void* d_ws, size_t ws_size,
                              hipStream_t stream) {
  (void)out_size; (void)ws_size;
  // size-based slot remap (no-op under documented dict order; protective otherwise)
  const int want[13] = {98304, 98304, 15360, 122880, 384, 384, 768, 256, 65536, 256, 768, 3, 5};
  int idx[13];
  bool used[64] = {false};
  for (int L = 0; L < 13; ++L) {
    idx[L] = -1;
    for (int s = 0; s < n_in && s < 64; ++s) {
      if (!used[s] && in_sizes[s] == want[L]) { idx[L] = s; used[s] = true; break; }
    }
    if (idx[L] < 0) idx[L] = L;
  }
  const float* pp0       = (const float*)d_in[idx[0]];
  const float* pp1       = (const float*)d_in[idx[1]];
  const float* part_pts  = (const float*)d_in[idx[2]];
  const float* part_pbw  = (const float*)d_in[idx[3]];
  const float* A         = (const float*)d_in[idx[4]];
  const float* bigA      = (const float*)d_in[idx[5]];
  const float* W1        = (const float*)d_in[idx[6]];
  const float* b1        = (const float*)d_in[idx[7]];
  const float* W2        = (const float*)d_in[idx[8]];
  const float* b2        = (const float*)d_in[idx[9]];
  const float* W3        = (const float*)d_in[idx[10]];
  const float* b3        = (const float*)d_in[idx[11]];
  const int*   lengths2  = (const int*)d_in[idx[12]];
  float* out = (float*)d_out;
  ushort_t* W2bf = (ushort_t*)d_ws;   // 128 KB of workspace

  nn_kernel<<<1536, 128, 0, stream>>>(pp0, pp1, part_pts, part_pbw,
                                      A, bigA, lengths2, W2, W2bf, out);
  mlp_kernel<<<2560, 256, 0, stream>>>(W1, b1, b2, W3, b3, W2bf, out);
}

// Round 16
// 160.167 us; speedup vs baseline: 1.1115x; 1.1115x over previous
//
#include <hip/hip_runtime.h>
#include <stdint.h>
#include <math.h>

// Problem constants
#define NPTS 32768
#define PP   5
#define MM   1024
#define JJ   24
#define HH   256

// out (f32 element offsets), total 2,293,760 floats
#define O0 0                // tpose        [1,N,P,3]
#define O1 491520           // tpose_dirs   [1,N,P,3]
#define O2 983040           // resd         [1,N,P,3]
#define O3 1474560          // pflag        [1,N,P]
#define O4 1638400          // init_bigpose [1,N*P,3]
#define O5 2129920          // pnorm        [1,N*P]

typedef unsigned short ushort_t;
typedef unsigned int   uint_t;
typedef unsigned long long u64_t;
typedef __attribute__((ext_vector_type(8))) short bf16x8;
typedef __attribute__((ext_vector_type(4))) float f32x4;
typedef __attribute__((ext_vector_type(2))) float f32x2;

__device__ __forceinline__ ushort_t f2bf(float f) {
  union { uint_t i; float f; } v; v.f = f;
  uint_t i = v.i;
  return (ushort_t)((i + 0x7FFFu + ((i >> 16) & 1u)) >> 16);  // RNE
}
// hardware packed f32->bf16 (RNE, bit-identical to f2bf for finite values)
__device__ __forceinline__ uint_t cvt_pk_bf16(float lo, float hi) {
  uint_t r;
  asm("v_cvt_pk_bf16_f32 %0, %1, %2" : "=v"(r) : "v"(lo), "v"(hi));
  return r;
}
__device__ __forceinline__ float tanh_fast(float v) {
  v = fminf(fmaxf(v, -15.f), 15.f);
  float e = __expf(2.f*v);               // v_exp_f32 path
  return __fdividef(e - 1.f, e + 1.f);   // abs err < 1e-6, plenty for tolerance
}
// 16-lane sum via DPP row_shl tree (VALU pipe). Result in lane m16==0.
__device__ __forceinline__ float dpp_sum16(float x) {
  x += __int_as_float(__builtin_amdgcn_update_dpp(0, __float_as_int(x), 0x108, 0xF, 0xF, true)); // row_shl:8
  x += __int_as_float(__builtin_amdgcn_update_dpp(0, __float_as_int(x), 0x104, 0xF, 0xF, true)); // row_shl:4
  x += __int_as_float(__builtin_amdgcn_update_dpp(0, __float_as_int(x), 0x102, 0xF, 0xF, true)); // row_shl:2
  x += __int_as_float(__builtin_amdgcn_update_dpp(0, __float_as_int(x), 0x101, 0xF, 0xF, true)); // row_shl:1
  return x;
}

// ---------------- LBS transform for one (n,p) row ----------------
__device__ __forceinline__ void transform_one(
    int n, int p, int nn, float pn, float fl,
    float px, float py, float pz, float dx, float dy, float dz,
    const float* __restrict__ pbw,
    const float4* __restrict__ sA4, const float4* __restrict__ sB4,
    float* __restrict__ out)
{
  const float4* bwr = (const float4*)(pbw + ((size_t)p * MM + nn) * JJ);
  float bw[24];
  #pragma unroll
  for (int q = 0; q < 6; ++q) {
    float4 u = bwr[q];
    bw[q*4+0] = u.x; bw[q*4+1] = u.y; bw[q*4+2] = u.z; bw[q*4+3] = u.w;
  }

  float M1[12], M2[12];
  #pragma unroll
  for (int q = 0; q < 12; ++q) { M1[q] = 0.f; M2[q] = 0.f; }
  #pragma unroll
  for (int j = 0; j < 24; ++j) {
    float w = bw[j];
    float4 a0 = sA4[j*3+0], a1 = sA4[j*3+1], a2 = sA4[j*3+2];
    M1[0]=fmaf(w,a0.x,M1[0]); M1[1]=fmaf(w,a0.y,M1[1]); M1[2]=fmaf(w,a0.z,M1[2]); M1[3]=fmaf(w,a0.w,M1[3]);
    M1[4]=fmaf(w,a1.x,M1[4]); M1[5]=fmaf(w,a1.y,M1[5]); M1[6]=fmaf(w,a1.z,M1[6]); M1[7]=fmaf(w,a1.w,M1[7]);
    M1[8]=fmaf(w,a2.x,M1[8]); M1[9]=fmaf(w,a2.y,M1[9]); M1[10]=fmaf(w,a2.z,M1[10]); M1[11]=fmaf(w,a2.w,M1[11]);
    float4 c0 = sB4[j*3+0], c1 = sB4[j*3+1], c2 = sB4[j*3+2];
    M2[0]=fmaf(w,c0.x,M2[0]); M2[1]=fmaf(w,c0.y,M2[1]); M2[2]=fmaf(w,c0.z,M2[2]); M2[3]=fmaf(w,c0.w,M2[3]);
    M2[4]=fmaf(w,c1.x,M2[4]); M2[5]=fmaf(w,c1.y,M2[5]); M2[6]=fmaf(w,c1.z,M2[6]); M2[7]=fmaf(w,c1.w,M2[7]);
    M2[8]=fmaf(w,c2.x,M2[8]); M2[9]=fmaf(w,c2.y,M2[9]); M2[10]=fmaf(w,c2.z,M2[10]); M2[11]=fmaf(w,c2.w,M2[11]);
  }
  float a=M1[0], b=M1[1], c=M1[2];
  float d=M1[4], e=M1[5], f=M1[6];
  float g=M1[8], h=M1[9], i=M1[10];
  float C00 = e*i - f*h, C01 = c*h - b*i, C02 = b*f - c*e;
  float C10 = f*g - d*i, C11 = a*i - c*g, C12 = c*d - a*f;
  float C20 = d*h - e*g, C21 = b*g - a*h, C22 = a*e - b*d;
  float det = a*C00 + b*C10 + c*C20;
  float rd = 1.0f / det;
  float tx = px - M1[3], ty = py - M1[7], tz = pz - M1[11];
  float t0 = rd * (C00*tx + C01*ty + C02*tz);
  float t1 = rd * (C10*tx + C11*ty + C12*tz);
  float t2 = rd * (C20*tx + C21*ty + C22*tz);
  float i0 = M2[0]*t0 + M2[1]*t1 + M2[2]*t2  + M2[3];
  float i1 = M2[4]*t0 + M2[5]*t1 + M2[6]*t2  + M2[7];
  float i2 = M2[8]*t0 + M2[9]*t1 + M2[10]*t2 + M2[11];
  float d0 = rd * (C00*dx + C01*dy + C02*dz);
  float d1 = rd * (C10*dx + C11*dy + C12*dz);
  float d2 = rd * (C20*dx + C21*dy + C22*dz);
  float e0 = M2[0]*d0 + M2[1]*d1 + M2[2]*d2;
  float e1 = M2[4]*d0 + M2[5]*d1 + M2[6]*d2;
  float e2 = M2[8]*d0 + M2[9]*d1 + M2[10]*d2;

  size_t k = (size_t)n * PP + p;   // n-major
  out[O1 + k*3+0] = e0; out[O1 + k*3+1] = e1; out[O1 + k*3+2] = e2;
  out[O3 + k] = fl;
  out[O4 + k*3+0] = i0; out[O4 + k*3+1] = i1; out[O4 + k*3+2] = i2;
  out[O5 + k] = pn;
}

// grid: 1536 blocks x 256 threads. Blocks >=1280 do the W2->bf16 prep.
// (round-13/14 verified nn: block-min scan + deterministic replay argmin;
// round-15's 8-pt/lane variant spilled to scratch and was reverted.)
__global__ __launch_bounds__(256) void nn_kernel(
    const float* __restrict__ pp0, const float* __restrict__ pp1,
    const float* __restrict__ part_pts, const float* __restrict__ pbw,
    const float* __restrict__ Ag, const float* __restrict__ Bg,
    const int* __restrict__ lengths2,
    const float* __restrict__ W2g, ushort_t* __restrict__ W2bf,
    float* __restrict__ out)
{
  // folded W2 prep (former prep_w2): blocks 1280..1535, k = bid-1280
  if (blockIdx.x >= 1280) {
    int k = blockIdx.x - 1280;
    int n = threadIdx.x;
    float v = W2g[k*256 + n];
    int kc = k >> 5, quad = (k & 31) >> 3, j = k & 7;
    int tile = n >> 4, lane = quad*16 + (n & 15);
    W2bf[kc*8192 + tile*512 + lane*8 + j] = f2bf(v);
    return;
  }

  __shared__ float4 sXq[256], sYq[256], sZq[256], sWq[256];  // SoA quads
  __shared__ float4 sA4[72];
  __shared__ float4 sB4[72];
  int t = threadIdx.x;
  int p  = blockIdx.x >> 8;        // 256 blocks per part
  int nb = blockIdx.x & 255;
  int g  = t >> 3;                 // n-group 0..31
  int s  = t & 7;                  // m-slice 0..7
  int n0 = nb*128 + g*4;           // this lane's 4 points: n0..n0+3

  // pose-pair disambiguation (wave-uniform); pose_dirs rows unit-norm
  float s0r0 = pp0[0], s0r1 = pp0[1], s0r2 = pp0[2];
  float nrm = s0r0*s0r0 + s0r1*s0r1 + s0r2*s0r2;
  bool c0_is_dirs = fabsf(nrm - 1.0f) < 1e-4f;
  const float* pose_pts  = c0_is_dirs ? pp1 : pp0;
  const float* pose_dirs = c0_is_dirs ? pp0 : pp1;

  {
    #pragma clang fp contract(off)
    float* fX = (float*)sXq; float* fY = (float*)sYq;
    float* fZ = (float*)sZq; float* fW = (float*)sWq;
    for (int i = t; i < MM; i += 256) {
      float x = part_pts[((size_t)p*MM+i)*3+0];
      float y = part_pts[((size_t)p*MM+i)*3+1];
      float z = part_pts[((size_t)p*MM+i)*3+2];
      float yy = ((x*x) + (y*y)) + (z*z);
      fX[i] = x; fY[i] = y; fZ[i] = z; fW[i] = yy;
    }
  }
  for (int i = t; i < 72; i += 256) {
    int l = i*4;
    int j = l / 12, rc = l % 12;
    float4 qa, qb;
    qa.x = Ag[j*16+rc+0]; qa.y = Ag[j*16+rc+1]; qa.z = Ag[j*16+rc+2]; qa.w = Ag[j*16+rc+3];
    qb.x = Bg[j*16+rc+0]; qb.y = Bg[j*16+rc+1]; qb.z = Bg[j*16+rc+2]; qb.w = Bg[j*16+rc+3];
    sA4[i] = qa; sB4[i] = qb;
  }
  int mlen = lengths2[p]; if (mlen > MM) mlen = MM;
  __syncthreads();

  // load 4 points' coordinates (n0 % 4 == 0 -> 16B aligned); build doubled splats
  float X[4], Y[4], Z[4];
  f32x2 Xd[4], Yd[4], Zd[4], C2[4];
  {
    #pragma clang fp contract(off)
    const float4* pr = (const float4*)(pose_pts + (size_t)n0*3);
    float4 f0 = pr[0], f1 = pr[1], f2 = pr[2];
    X[0]=f0.x; Y[0]=f0.y; Z[0]=f0.z;
    X[1]=f0.w; Y[1]=f1.x; Z[1]=f1.y;
    X[2]=f1.z; Y[2]=f1.w; Z[2]=f2.x;
    X[3]=f2.y; Y[3]=f2.z; Z[3]=f2.w;
    #pragma unroll
    for (int j = 0; j < 4; ++j) {
      float x2 = ((X[j]*X[j]) + (Y[j]*Y[j])) + (Z[j]*Z[j]);
      Xd[j] = (f32x2){2.0f*X[j], 2.0f*X[j]};
      Yd[j] = (f32x2){2.0f*Y[j], 2.0f*Y[j]};
      Zd[j] = (f32x2){2.0f*Z[j], 2.0f*Z[j]};
      C2[j] = (f32x2){x2, x2};
    }
  }

  float best[4]  = {INFINITY, INFINITY, INFINITY, INFINITY};
  int   kb[4]    = {0, 0, 0, 0};   // winning 32-block id (main scan)
  int   mbest[4] = {0, 0, 0, 0};   // final m index
  int   nq = mlen >> 5;            // full 32-blocks
  {
    #pragma clang fp contract(off)
    for (int k = 0; k < nq; ++k) {
      int qi = k*8 + s;                // quad index (8-way same-addr broadcast)
      float4 QX = sXq[qi], QY = sYq[qi], QZ = sZq[qi], QW = sWq[qi];
      f32x2 qx0 = {QX.x, QX.y}, qx1 = {QX.z, QX.w};
      f32x2 qy0 = {QY.x, QY.y}, qy1 = {QY.z, QY.w};
      f32x2 qz0 = {QZ.x, QZ.y}, qz1 = {QZ.z, QZ.w};
      f32x2 qw0 = {QW.x, QW.y}, qw1 = {QW.z, QW.w};
      #pragma unroll
      for (int j = 0; j < 4; ++j) {
        f32x2 dt0 = ((Xd[j]*qx0) + (Yd[j]*qy0)) + (Zd[j]*qz0);
        f32x2 tt0 = (C2[j] - dt0) + qw0;
        f32x2 dt1 = ((Xd[j]*qx1) + (Yd[j]*qy1)) + (Zd[j]*qz1);
        f32x2 tt1 = (C2[j] - dt1) + qw1;
        float e0 = fmaxf(tt0.x, 0.f);
        float e1 = fmaxf(tt0.y, 0.f);
        float e2 = fmaxf(tt1.x, 0.f);
        float e3 = fmaxf(tt1.y, 0.f);
        float m01 = fminf(e0, e1);
        float m23 = fminf(e2, e3);
        float lmin = fminf(m01, m23);
        bool lt = lmin < best[j];            // strict: first block keeps win
        best[j] = fminf(best[j], lmin);
        kb[j] = lt ? k : kb[j];
      }
    }
    // deterministic replay of the winning block -> exact first-min index
    if (nq > 0) {
      #pragma unroll
      for (int j = 0; j < 4; ++j) {
        int qi = kb[j]*8 + s;
        float4 QX = sXq[qi], QY = sYq[qi], QZ = sZq[qi], QW = sWq[qi];
        float dA = ((Xd[j].x*QX.x) + (Yd[j].x*QY.x)) + (Zd[j].x*QZ.x);
        float eA = fmaxf((C2[j].x - dA) + QW.x, 0.f);
        float dB = ((Xd[j].x*QX.y) + (Yd[j].x*QY.y)) + (Zd[j].x*QZ.y);
        float eB = fmaxf((C2[j].x - dB) + QW.y, 0.f);
        float dC = ((Xd[j].x*QX.z) + (Yd[j].x*QY.z)) + (Zd[j].x*QZ.z);
        float eC = fmaxf((C2[j].x - dC) + QW.z, 0.f);
        // first element equal to best (eD implied if others miss)
        int e = (eA == best[j]) ? 0 : (eB == best[j]) ? 1 : (eC == best[j]) ? 2 : 3;
        mbest[j] = (kb[j] << 5) + 4*s + e;
      }
    } else {
      #pragma unroll
      for (int j = 0; j < 4; ++j) mbest[j] = 4*s;
    }
    // tail: partial 32-block (not taken when mlen % 32 == 0)
    int mb0 = nq << 5;
    if (mb0 < mlen) {
      const float* fX = (const float*)sXq; const float* fY = (const float*)sYq;
      const float* fZ = (const float*)sZq; const float* fW = (const float*)sWq;
      #pragma unroll
      for (int e = 0; e < 4; ++e) {
        int m = mb0 + 4*s + e;
        if (m < mlen) {
          float qx = fX[m], qy = fY[m], qz = fZ[m], qw = fW[m];
          #pragma unroll
          for (int j = 0; j < 4; ++j) {
            float dt2 = ((Xd[j].x*qx) + (Yd[j].x*qy)) + (Zd[j].x*qz);
            float dd = fmaxf((C2[j].x - dt2) + qw, 0.0f);
            bool lt = dd < best[j];          // strict: earlier m wins ties
            best[j] = fminf(best[j], dd);
            mbest[j] = lt ? m : mbest[j];
          }
        }
      }
    }
  }

  // merge the 8 slices (butterfly within each 8-lane group), lexicographic
  u64_t pk[4];
  #pragma unroll
  for (int j = 0; j < 4; ++j) {
    pk[j] = ((u64_t)__float_as_uint(best[j]) << 32) | (uint_t)mbest[j];
    u64_t o;
    o = __shfl_xor(pk[j], 1); if (o < pk[j]) pk[j] = o;
    o = __shfl_xor(pk[j], 2); if (o < pk[j]) pk[j] = o;
    o = __shfl_xor(pk[j], 4); if (o < pk[j]) pk[j] = o;
  }

  // lanes s=0..3 each transform one point (no redistribution shuffles)
  if (s < 4) {
    u64_t mypk = (s==0) ? pk[0] : (s==1) ? pk[1] : (s==2) ? pk[2] : pk[3];
    float xa = (s==0) ? X[0] : (s==1) ? X[1] : (s==2) ? X[2] : X[3];
    float ya = (s==0) ? Y[0] : (s==1) ? Y[1] : (s==2) ? Y[2] : Y[3];
    float za = (s==0) ? Z[0] : (s==1) ? Z[1] : (s==2) ? Z[2] : Z[3];
    int n = n0 + s;
    int bm = (int)(mypk & 0xFFFFFFFFull);
    float bd = __uint_as_float((uint_t)(mypk >> 32));
    float pn = sqrtf(bd);
    float fl = ((double)pn < 0.08) ? 1.0f : 0.0f;
    float dxa = pose_dirs[n*3+0], dya = pose_dirs[n*3+1], dza = pose_dirs[n*3+2];
    transform_one(n, p, bm, pn, fl, xa, ya, za, dxa, dya, dza, pbw, sA4, sB4, out);
  }
}

// ---------------- MLP: r14-verified (conflict-free build) ----------------
// grid: 2560 blocks x 256 threads (4 waves); block = 64 rows x 256 cols,
// single pass. Build: thread t owns ROW r = t&63 and iterates its wave's 8
// col-octets -> store lanes vary r15 -> bank-spread writes (r13's col-octet
// mapping had 9.17M conflicts; this layout ~20K). h1 exprs / cvt_pk pairing /
// sH layout (entry = qd*16+r15) / K-loop / epilogue verified in r14.
__global__ __launch_bounds__(256) void mlp_kernel(
    const float* __restrict__ W1g, const float* __restrict__ b1g,
    const float* __restrict__ b2g, const float* __restrict__ W3g,
    const float* __restrict__ b3g, const ushort_t* __restrict__ W2bf,
    float* __restrict__ out)
{
  __shared__ ushort_t sH[4*8*512];   // 32KB: h1 A-frags [mt][kc][qd*16+r15][8]
  __shared__ float4 w1c[256];        // {W1[0][c], W1[1][c], W1[2][c], b1[c]}
  __shared__ float4 w3b2[256];       // {W3[c][0], W3[c][1], W3[c][2], b2[c]}
  __shared__ float4 sRow[64];        // {x, y, z, pflag} per row
  __shared__ float  prt[64][4][3];   // per-row layer-3 partials per wave

  int t = threadIdx.x;
  int wave = t >> 6, lane = t & 63, quad = lane >> 4, m16 = lane & 15;
  size_t row0 = (size_t)blockIdx.x * 64;

  {
    int c = t;   // 256 threads exactly
    w1c[c]  = make_float4(W1g[c], W1g[256+c], W1g[512+c], b1g[c]);
    w3b2[c] = make_float4(W3g[c*3+0], W3g[c*3+1], W3g[c*3+2], b2g[c]);
    if (t < 64) {
      size_t r = row0 + t;
      sRow[t] = make_float4(out[O4 + r*3+0], out[O4 + r*3+1], out[O4 + r*3+2],
                            out[O3 + r]);
    }
  }
  __syncthreads();

  // build sH: thread t -> row r = t&63; octets o = (t>>6)*8 + j (j=0..7).
  {
    int r = t & 63;
    float4 xyz = sRow[r];
    int mt = r >> 4, r15 = r & 15;
    #pragma unroll
    for (int j = 0; j < 8; ++j) {
      int o = wave*8 + j;
      int kcw = o >> 2, qd = o & 3;
      int c0 = kcw*32 + qd*8;
      uint_t u0, u1, u2, u3;
      {
        float4 wA = w1c[c0 + 0], wB = w1c[c0 + 1];
        float hA = fmaxf(fmaf(xyz.z, wA.z, fmaf(xyz.y, wA.y, fmaf(xyz.x, wA.x, wA.w))), 0.f);
        float hB = fmaxf(fmaf(xyz.z, wB.z, fmaf(xyz.y, wB.y, fmaf(xyz.x, wB.x, wB.w))), 0.f);
        u0 = cvt_pk_bf16(hA, hB);
      }
      {
        float4 wA = w1c[c0 + 2], wB = w1c[c0 + 3];
        float hA = fmaxf(fmaf(xyz.z, wA.z, fmaf(xyz.y, wA.y, fmaf(xyz.x, wA.x, wA.w))), 0.f);
        float hB = fmaxf(fmaf(xyz.z, wB.z, fmaf(xyz.y, wB.y, fmaf(xyz.x, wB.x, wB.w))), 0.f);
        u1 = cvt_pk_bf16(hA, hB);
      }
      {
        float4 wA = w1c[c0 + 4], wB = w1c[c0 + 5];
        float hA = fmaxf(fmaf(xyz.z, wA.z, fmaf(xyz.y, wA.y, fmaf(xyz.x, wA.x, wA.w))), 0.f);
        float hB = fmaxf(fmaf(xyz.z, wB.z, fmaf(xyz.y, wB.y, fmaf(xyz.x, wB.x, wB.w))), 0.f);
        u2 = cvt_pk_bf16(hA, hB);
      }
      {
        float4 wA = w1c[c0 + 6], wB = w1c[c0 + 7];
        float hA = fmaxf(fmaf(xyz.z, wA.z, fmaf(xyz.y, wA.y, fmaf(xyz.x, wA.x, wA.w))), 0.f);
        float hB = fmaxf(fmaf(xyz.z, wB.z, fmaf(xyz.y, wB.y, fmaf(xyz.x, wB.x, wB.w))), 0.f);
        u3 = cvt_pk_bf16(hA, hB);
      }
      *(uint4*)(&sH[((mt*8 + kcw)*64 + qd*16 + r15)*8]) = make_uint4(u0, u1, u2, u3);
    }
  }
  __syncthreads();

  // K-loop: wave owns cols nt in [wave*4, wave*4+4)
  const ushort_t* Wlane = W2bf + (size_t)wave*2048 + lane*8;
  bf16x8 Bcur[4], Bnxt[4];
  #pragma unroll
  for (int q = 0; q < 4; ++q) Bcur[q] = *(const bf16x8*)(Wlane + q*512);  // kc=0

  f32x4 acc[16];                   // acc[mt*4+q]
  #pragma unroll
  for (int i = 0; i < 16; ++i) acc[i] = (f32x4){0.f,0.f,0.f,0.f};

  #pragma unroll 1
  for (int kc = 0; kc < 8; ++kc) {
    bf16x8 Af[4];
    #pragma unroll
    for (int mt = 0; mt < 4; ++mt)
      Af[mt] = *(const bf16x8*)(&sH[((mt*8 + kc)*64 + lane)*8]);
    if (kc < 7) {                  // prefetch next kc's B under this kc's MFMAs
      #pragma unroll
      for (int q = 0; q < 4; ++q)
        Bnxt[q] = *(const bf16x8*)(Wlane + (kc+1)*8192 + q*512);
    }
    #pragma unroll
    for (int mt = 0; mt < 4; ++mt)
      #pragma unroll
      for (int q = 0; q < 4; ++q)
        acc[mt*4+q] = __builtin_amdgcn_mfma_f32_16x16x32_bf16(Af[mt], Bcur[q], acc[mt*4+q], 0, 0, 0);
    if (kc < 7) {
      #pragma unroll
      for (int q = 0; q < 4; ++q) Bcur[q] = Bnxt[q];
    }
  }

  // epilogue: h2[row=mt*16+quad*4+reg][col=(wave*4+q)*16+m16] = acc[mt*4+q][reg]
  float4 cvq[4];
  #pragma unroll
  for (int q = 0; q < 4; ++q) cvq[q] = w3b2[(wave*4+q)*16 + m16];

  #pragma unroll
  for (int mt = 0; mt < 4; ++mt) {
    #pragma unroll
    for (int reg = 0; reg < 4; ++reg) {
      float q0 = 0.f, q1 = 0.f, q2 = 0.f;
      #pragma unroll
      for (int q = 0; q < 4; ++q) {
        float h2 = fmaxf(acc[mt*4+q][reg] + cvq[q].w, 0.f);
        q0 = fmaf(h2, cvq[q].x, q0);
        q1 = fmaf(h2, cvq[q].y, q1);
        q2 = fmaf(h2, cvq[q].z, q2);
      }
      q0 = dpp_sum16(q0);
      q1 = dpp_sum16(q1);
      q2 = dpp_sum16(q2);
      if (m16 == 0) {
        int lr = mt*16 + quad*4 + reg;           // local row 0..63
        prt[lr][wave][0] = q0;
        prt[lr][wave][1] = q1;
        prt[lr][wave][2] = q2;
      }
    }
  }
  __syncthreads();

  // combine: thread t -> (row = t>>2, comp = t&3), comp<3 active
  {
    int lr = t >> 2, c = t & 3;
    if (c < 3) {
      float v = ((prt[lr][0][c] + prt[lr][1][c]) + prt[lr][2][c]) + prt[lr][3][c];
      size_t r = row0 + lr;
      float4 ib = sRow[lr];
      float iv = (c == 0) ? ib.x : (c == 1) ? ib.y : ib.z;
      float rr = 0.05f * tanh_fast(v + b3g[c]) * ib.w;
      out[O0 + r*3 + c] = iv + rr;
      out[O2 + r*3 + c] = rr;
    }
  }
}

extern "C" void kernel_launch(void* const* d_in, const int* in_sizes, int n_in,
                              void* d_out, int out_size, void* d_ws, size_t ws_size,
                              hipStream_t stream) {
  (void)out_size; (void)ws_size;
  // size-based slot remap (no-op under documented dict order; protective otherwise)
  const int want[13] = {98304, 98304, 15360, 122880, 384, 384, 768, 256, 65536, 256, 768, 3, 5};
  int idx[13];
  bool used[64] = {false};
  for (int L = 0; L < 13; ++L) {
    idx[L] = -1;
    for (int s = 0; s < n_in && s < 64; ++s) {
      if (!used[s] && in_sizes[s] == want[L]) { idx[L] = s; used[s] = true; break; }
    }
    if (idx[L] < 0) idx[L] = L;
  }
  const float* pp0       = (const float*)d_in[idx[0]];
  const float* pp1       = (const float*)d_in[idx[1]];
  const float* part_pts  = (const float*)d_in[idx[2]];
  const float* part_pbw  = (const float*)d_in[idx[3]];
  const float* A         = (const float*)d_in[idx[4]];
  const float* bigA      = (const float*)d_in[idx[5]];
  const float* W1        = (const float*)d_in[idx[6]];
  const float* b1        = (const float*)d_in[idx[7]];
  const float* W2        = (const float*)d_in[idx[8]];
  const float* b2        = (const float*)d_in[idx[9]];
  const float* W3        = (const float*)d_in[idx[10]];
  const float* b3        = (const float*)d_in[idx[11]];
  const int*   lengths2  = (const int*)d_in[idx[12]];
  float* out = (float*)d_out;
  ushort_t* W2bf = (ushort_t*)d_ws;   // 128 KB of workspace

  nn_kernel<<<1536, 256, 0, stream>>>(pp0, pp1, part_pts, part_pbw,
                                      A, bigA, lengths2, W2, W2bf, out);
  mlp_kernel<<<2560, 256, 0, stream>>>(W1, b1, b2, W3, b3, W2bf, out);
}